// Round 8
// baseline (132.174 us; speedup 1.0000x reference)
//
#include <hip/hip_runtime.h>
#include <math.h>

#define BB 4
#define SQL 512
#define SKL 512
#define HH 256
#define AA 128

// 2 * log2(e): Qt/Kt pre-scaled so the score loop feeds v_exp_f32 (2^x) directly.
#define PRESCALE 2.8853900817779268f

__device__ inline void fma4(float4& a, float s, const float4& b) {
    a.x = fmaf(s, b.x, a.x); a.y = fmaf(s, b.y, a.y);
    a.z = fmaf(s, b.z, a.z); a.w = fmaf(s, b.w, a.w);
}

__device__ inline unsigned short f_to_bf16(float f) {   // round-to-nearest-even
    unsigned u = __float_as_uint(f);
    return (unsigned short)((u + 0x7fffu + ((u >> 16) & 1u)) >> 16);
}
__device__ inline float4 bf16x4_to_f4(uint2 u) {
    float4 r;
    r.x = __uint_as_float(u.x << 16);
    r.y = __uint_as_float(u.x & 0xffff0000u);
    r.z = __uint_as_float(u.y << 16);
    r.w = __uint_as_float(u.y & 0xffff0000u);
    return r;
}

// ---------------------------------------------------------------------------
// Kernel 1 "prep" (unchanged from R7): Qt/Kt prescaled projections, VW bf16.
// grid 256 x 256 thr (1 block/CU). Block = 32 rows x 128 cols; thread = 4x4.
// ---------------------------------------------------------------------------
__global__ __launch_bounds__(256) void prep_kernel(
    const float* __restrict__ Q, const float* __restrict__ K,
    const float* __restrict__ V,
    const float* __restrict__ Wq, const float* __restrict__ Wk,
    const float* __restrict__ Wo,
    float* __restrict__ Qt, float* __restrict__ Kt,
    unsigned short* __restrict__ VW)
{
    __shared__ float rowsT[256 * 36];    // 36 KB, rowsT[k*36 + r]
    int tid = threadIdx.x;
    int bid = blockIdx.x;

    const float* X; const float* W;
    int ldW, col0, r0, kind;
    if (bid < 64)       { X=Q; W=Wq; ldW=AA; kind=0; r0=bid*32;      col0=0; }
    else if (bid < 128) { X=K; W=Wk; ldW=AA; kind=1; r0=(bid-64)*32; col0=0; }
    else { int b2=bid-128; X=V; W=Wo; ldW=HH; kind=2; r0=(b2>>1)*32; col0=(b2&1)*128; }

    {
        const float4* Xv = (const float4*)(X + (size_t)r0 * HH);
        #pragma unroll
        for (int it = 0; it < 8; ++it) {
            int l = tid + it * 256;          // 2048 float4
            int r = l >> 6, k4 = (l & 63) << 2;
            float4 x = Xv[l];
            rowsT[(k4 + 0) * 36 + r] = x.x;
            rowsT[(k4 + 1) * 36 + r] = x.y;
            rowsT[(k4 + 2) * 36 + r] = x.z;
            rowsT[(k4 + 3) * 36 + r] = x.w;
        }
    }

    int mg = tid >> 5;           // 4-row group
    int n4 = tid & 31;           // float4 col
    int mbase = mg << 2;
    const float* Wg = W + col0 + (n4 << 2);

    float4 acc0 = {0,0,0,0}, acc1 = {0,0,0,0}, acc2 = {0,0,0,0}, acc3 = {0,0,0,0};
    float4 wA[4], wB[4];
    #pragma unroll
    for (int j = 0; j < 4; ++j)
        wA[j] = *(const float4*)(Wg + (size_t)j * ldW);
    __syncthreads();

    for (int g = 0; g < 64; g += 2) {
        #pragma unroll
        for (int j = 0; j < 4; ++j)
            wB[j] = *(const float4*)(Wg + (size_t)((g + 1) * 4 + j) * ldW);
        {
            float4 a[4];
            #pragma unroll
            for (int j = 0; j < 4; ++j)
                a[j] = *(const float4*)&rowsT[(g * 4 + j) * 36 + mbase];
            #pragma unroll
            for (int j = 0; j < 4; ++j) {
                fma4(acc0, a[j].x, wA[j]);
                fma4(acc1, a[j].y, wA[j]);
                fma4(acc2, a[j].z, wA[j]);
                fma4(acc3, a[j].w, wA[j]);
            }
        }
        if (g + 2 < 64) {
            #pragma unroll
            for (int j = 0; j < 4; ++j)
                wA[j] = *(const float4*)(Wg + (size_t)((g + 2) * 4 + j) * ldW);
        }
        {
            float4 a[4];
            #pragma unroll
            for (int j = 0; j < 4; ++j)
                a[j] = *(const float4*)&rowsT[((g + 1) * 4 + j) * 36 + mbase];
            #pragma unroll
            for (int j = 0; j < 4; ++j) {
                fma4(acc0, a[j].x, wB[j]);
                fma4(acc1, a[j].y, wB[j]);
                fma4(acc2, a[j].z, wB[j]);
                fma4(acc3, a[j].w, wB[j]);
            }
        }
    }

    if (kind < 2) {
        float* Y = (kind == 0) ? Qt : Kt;
        float4 av[4] = {acc0, acc1, acc2, acc3};
        #pragma unroll
        for (int i = 0; i < 4; ++i) {
            float4 s = av[i];
            s.x *= PRESCALE; s.y *= PRESCALE; s.z *= PRESCALE; s.w *= PRESCALE;
            *(float4*)(Y + (size_t)(r0 + mbase + i) * AA + (n4 << 2)) = s;
        }
    } else {
        float4 av[4] = {acc0, acc1, acc2, acc3};
        #pragma unroll
        for (int i = 0; i < 4; ++i) {
            ushort4 s = { f_to_bf16(av[i].x), f_to_bf16(av[i].y),
                          f_to_bf16(av[i].z), f_to_bf16(av[i].w) };
            *(ushort4*)(VW + (size_t)(r0 + mbase + i) * HH + col0 + (n4 << 2)) = s;
        }
    }
}

// ---------------------------------------------------------------------------
// Kernel 2 "score_part": raw scores for one (batch, q-pair, k-half).
// grid = 2048 blocks x 256 thr (8 blocks/CU).
// R5 thread mapping restored: ag = tid&7 owns 16 a's, kl = tid>>3, chunk =
// 32 k-rows, j=16 -> only 6 shfl per chunk against 48 trans-instrs (9%
// cross-lane overhead vs 50% in the R6/R7 mapping — the hidden regression).
// q-pair shares exp2 via d[j] = 2^(Qt1-Qt0); next Kt chunk reg-prefetched.
// ---------------------------------------------------------------------------
__global__ __launch_bounds__(256) void score_part(
    const float* __restrict__ Qt, const float* __restrict__ Kt,
    const float* __restrict__ v,  float* __restrict__ scores)
{
    __shared__ float sc[2][256];         // 2 KB

    int tid = threadIdx.x;
    int bid = blockIdx.x;
    int b    = bid >> 9;                 // 512 blocks per batch
    int rem  = bid & 511;
    int q0   = rem & ~1;                 // q-pair base
    int half = rem & 1;                  // k-half: [256*half, 256*half+256)
    int ag = tid & 7;                    // a-range [16ag, 16ag+16)
    int kl = tid >> 3;                   // k within 32-chunk

    // register caches: Qt row0 (prescaled), d = 2^(q1-q0), 2*v  (16-wide)
    float q0r[16], dr[16], v2[16];
    {
        const float4* vp  = (const float4*)(v + ag * 16);
        const float4* qp0 = (const float4*)(Qt + (size_t)(b * SQL + q0)     * AA + ag * 16);
        const float4* qp1 = (const float4*)(Qt + (size_t)(b * SQL + q0 + 1) * AA + ag * 16);
        #pragma unroll
        for (int j4 = 0; j4 < 4; ++j4) {
            float4 vv4 = vp[j4];
            float4 a0  = qp0[j4];
            float4 a1  = qp1[j4];
            *(float4*)&q0r[j4 * 4] = a0;
            dr[j4*4+0] = __builtin_amdgcn_exp2f(a1.x - a0.x);
            dr[j4*4+1] = __builtin_amdgcn_exp2f(a1.y - a0.y);
            dr[j4*4+2] = __builtin_amdgcn_exp2f(a1.z - a0.z);
            dr[j4*4+3] = __builtin_amdgcn_exp2f(a1.w - a0.w);
            v2[j4*4+0] = 2.0f * vv4.x;
            v2[j4*4+1] = 2.0f * vv4.y;
            v2[j4*4+2] = 2.0f * vv4.z;
            v2[j4*4+3] = 2.0f * vv4.w;
        }
    }

    // S_all = sum_a v[a]: local partial then xor-reduce over the 8 ag-lanes
    float S_all;
    {
        float ls = 0.f;
        #pragma unroll
        for (int j = 0; j < 16; ++j) ls += v2[j];
        ls += __shfl_xor(ls, 1);
        ls += __shfl_xor(ls, 2);
        ls += __shfl_xor(ls, 4);
        S_all = 0.5f * ls;
    }

    // main loop: 8 chunks x 32 k-rows; next Kt chunk register-prefetched
    const float4* kp = (const float4*)(Kt + (size_t)(b * SKL + half * 256 + kl) * AA + ag * 16);
    float4 n0 = kp[0], n1 = kp[1], n2 = kp[2], n3 = kp[3];
    for (int c = 0; c < 8; ++c) {
        float kt[16];
        *(float4*)&kt[0]  = n0;
        *(float4*)&kt[4]  = n1;
        *(float4*)&kt[8]  = n2;
        *(float4*)&kt[12] = n3;
        if (c < 7) {
            const float4* np = kp + (size_t)(c + 1) * 32 * (AA / 4);
            n0 = np[0]; n1 = np[1]; n2 = np[2]; n3 = np[3];
        }

        float p0 = 0.f, p1 = 0.f;
        #pragma unroll
        for (int j = 0; j < 16; ++j) {
            float x0 = q0r[j] + kt[j];
            float e0 = __builtin_amdgcn_exp2f(x0);
            float e1 = e0 * dr[j];                  // = 2^(q1+kv)
            float r0 = __builtin_amdgcn_rcpf(e0 + 1.0f);
            float r1 = __builtin_amdgcn_rcpf(e1 + 1.0f);
            p0 = fmaf(v2[j], r0, p0);
            p1 = fmaf(v2[j], r1, p1);
        }
        p0 += __shfl_xor(p0, 1); p1 += __shfl_xor(p1, 1);
        p0 += __shfl_xor(p0, 2); p1 += __shfl_xor(p1, 2);
        p0 += __shfl_xor(p0, 4); p1 += __shfl_xor(p1, 4);
        if (ag == 0) {
            sc[0][c * 32 + kl] = S_all - p0;
            sc[1][c * 32 + kl] = S_all - p1;
        }
    }
    __syncthreads();

    if (tid < 128) {    // vectored store of the 2x256 raw scores
        int q = tid >> 6, i = tid & 63;
        float4 val = *(float4*)&sc[q][i << 2];
        *(float4*)(scores + (size_t)(b * SQL + q0 + q) * SKL + half * 256 + (i << 2)) = val;
    }
}

// ---------------------------------------------------------------------------
// Kernel 3 "softepi" (unchanged from R7): softmax in place + weights@VW + b_o.
// grid = 512 blocks x 256 thr, block = (batch, 4 q-rows).
// ---------------------------------------------------------------------------
__global__ __launch_bounds__(256) void softepi_kernel(
    const unsigned short* __restrict__ VW, const float* __restrict__ bo,
    float* __restrict__ weights, float* __restrict__ out)
{
    __shared__ float sw[4][SKL];         // 8 KB
    __shared__ float pout[4][4][HH];     // 16 KB

    int tid = threadIdx.x;
    int b  = blockIdx.x >> 7;            // 128 blocks per batch
    int q0 = (blockIdx.x & 127) << 2;    // 4 q-rows
    int wave = tid >> 6, lane = tid & 63;

    {
        float* wrow = weights + (size_t)(b * SQL + q0 + wave) * SKL;
        float4 s0 = *(float4*)(wrow + (lane << 2));
        float4 s1 = *(float4*)(wrow + 256 + (lane << 2));
        float m = fmaxf(fmaxf(fmaxf(s0.x, s0.y), fmaxf(s0.z, s0.w)),
                        fmaxf(fmaxf(s1.x, s1.y), fmaxf(s1.z, s1.w)));
        #pragma unroll
        for (int off = 32; off; off >>= 1) m = fmaxf(m, __shfl_xor(m, off));
        float4 e0, e1;
        e0.x = __builtin_amdgcn_exp2f((s0.x - m) * 1.44269504f);
        e0.y = __builtin_amdgcn_exp2f((s0.y - m) * 1.44269504f);
        e0.z = __builtin_amdgcn_exp2f((s0.z - m) * 1.44269504f);
        e0.w = __builtin_amdgcn_exp2f((s0.w - m) * 1.44269504f);
        e1.x = __builtin_amdgcn_exp2f((s1.x - m) * 1.44269504f);
        e1.y = __builtin_amdgcn_exp2f((s1.y - m) * 1.44269504f);
        e1.z = __builtin_amdgcn_exp2f((s1.z - m) * 1.44269504f);
        e1.w = __builtin_amdgcn_exp2f((s1.w - m) * 1.44269504f);
        float s = ((e0.x + e0.y) + (e0.z + e0.w)) + ((e1.x + e1.y) + (e1.z + e1.w));
        #pragma unroll
        for (int off = 32; off; off >>= 1) s += __shfl_xor(s, off);
        float rinv = 1.0f / s;
        float4 w0 = { e0.x * rinv, e0.y * rinv, e0.z * rinv, e0.w * rinv };
        float4 w1 = { e1.x * rinv, e1.y * rinv, e1.z * rinv, e1.w * rinv };
        *(float4*)&sw[wave][lane << 2]         = w0;
        *(float4*)&sw[wave][256 + (lane << 2)] = w1;
        *(float4*)(wrow + (lane << 2))       = w0;
        *(float4*)(wrow + 256 + (lane << 2)) = w1;
    }
    __syncthreads();

    {
        const uint2* VWb = (const uint2*)(VW + (size_t)b * SKL * HH);
        float4 a0 = {0,0,0,0}, a1 = {0,0,0,0}, a2 = {0,0,0,0}, a3 = {0,0,0,0};
        int kbase = wave * 128;
        for (int k4 = 0; k4 < 32; ++k4) {
            int kk = kbase + k4 * 4;
            float4 w0 = *(const float4*)&sw[0][kk];
            float4 w1 = *(const float4*)&sw[1][kk];
            float4 w2 = *(const float4*)&sw[2][kk];
            float4 w3 = *(const float4*)&sw[3][kk];
            #pragma unroll
            for (int j = 0; j < 4; ++j) {
                uint2 u = VWb[(size_t)(kk + j) * (HH / 4) + lane];
                float4 vw4 = bf16x4_to_f4(u);
                fma4(a0, ((const float*)&w0)[j], vw4);
                fma4(a1, ((const float*)&w1)[j], vw4);
                fma4(a2, ((const float*)&w2)[j], vw4);
                fma4(a3, ((const float*)&w3)[j], vw4);
            }
        }
        *(float4*)&pout[wave][0][lane << 2] = a0;
        *(float4*)&pout[wave][1][lane << 2] = a1;
        *(float4*)&pout[wave][2][lane << 2] = a2;
        *(float4*)&pout[wave][3][lane << 2] = a3;
    }
    __syncthreads();
    {
        int h = tid;
        float bias = bo[h];
        #pragma unroll
        for (int q2 = 0; q2 < 4; ++q2) {
            float s = bias + pout[0][q2][h] + pout[1][q2][h]
                           + pout[2][q2][h] + pout[3][q2][h];
            out[(size_t)(b * SQL + q0 + q2) * HH + h] = s;
        }
    }
}

// ---------------------------------------------------------------------------
extern "C" void kernel_launch(void* const* d_in, const int* in_sizes, int n_in,
                              void* d_out, int out_size, void* d_ws, size_t ws_size,
                              hipStream_t stream)
{
    const float* Q  = (const float*)d_in[0];
    const float* K  = (const float*)d_in[1];
    const float* V  = (const float*)d_in[2];
    const float* Wq = (const float*)d_in[3];
    const float* Wk = (const float*)d_in[4];
    const float* v  = (const float*)d_in[5];
    const float* Wo = (const float*)d_in[6];
    const float* bo = (const float*)d_in[7];

    float* out     = (float*)d_out;                   // (B,SQ,H) = 524288
    float* weights = out + (size_t)BB * SQL * HH;     // (B,SQ,SK) = 1048576

    float* Qt = (float*)d_ws;                         // 262144 floats
    float* Kt = Qt + (size_t)BB * SQL * AA;           // 262144 floats
    unsigned short* VW = (unsigned short*)(Kt + (size_t)BB * SKL * AA); // 524288 bf16

    prep_kernel   <<<256, 256, 0, stream>>>(Q, K, V, Wq, Wk, Wo, Qt, Kt, VW);
    score_part    <<<2048, 256, 0, stream>>>(Qt, Kt, v, weights);
    softepi_kernel<<<512, 256, 0, stream>>>(VW, bo, weights, out);
}